// Round 17
// baseline (205.100 us; speedup 1.0000x reference)
//
#include <hip/hip_runtime.h>
#include <hip/hip_bf16.h>

#define B_  64
#define L_  50
#define A_  256
#define F_  8
#define E_  64
#define P_  4096
#define NF_ 128

typedef __attribute__((ext_vector_type(8))) short bhalf8;
typedef __attribute__((ext_vector_type(4))) float f32x4;

union BF { bhalf8 v; unsigned u[4]; short s[8]; };

static __device__ __forceinline__ unsigned pk2(float lo, float hi) {
    __hip_bfloat162 h = __float22bfloat162_rn(float2{lo, hi});  // RNE, lo in low 16
    union { __hip_bfloat162 h; unsigned u; } c; c.h = h;
    return c.u;
}

// Fragment convention (verified passing rounds 4/5/7/15, absmax <= 0.0176):
//   A-frag (lane l): row=l&15,  k=32s+8*(l>>4)+j (j=0..7)
//   B-frag (lane l): col=l&15,  same k
//   C/D   (lane l): col=l&15,  row=4*(l>>4)+reg
//
// PROBE ROUND: kernels identical to round 15; enc and cls launched 3x each
// (idempotent). dur_delta vs round 15 = 2*(enc+cls) -> separates kernel cost
// from the fixed harness floor (ws re-poison fillBuffer ~45us + restores).
//
// ws layout: frags[136][64] uint4 at offset 0 (139,264 B); emb (4 MB fp32) at
// float offset 65536 (256 KB).

#define ENC_KSTEPS 13
#define FRAG_TOTAL 136
#define W1_FRAG_OFF (104 * 64)
#define EMB_OFF 65536

// ---------------- wprep: pack Wf/Wu/W1 into bf16 MFMA B-fragments ----------
__global__ __launch_bounds__(256) void wprep_kernel(
    const float* __restrict__ Wf, const float* __restrict__ Wu,
    const float* __restrict__ W1, uint4* __restrict__ frags) {
    const int gid = blockIdx.x * 256 + threadIdx.x;
    if (gid >= FRAG_TOTAL * 64) return;
    const int fid = gid >> 6, lane = gid & 63;
    const int r = lane & 15, g = lane >> 4;
    const float* W; int s, t, K;
    if (fid < 104) {
        const int role = fid / 52, sf = fid % 52;
        s = sf >> 2; t = sf & 3; W = role ? Wu : Wf; K = 400;
    } else {
        const int st = fid - 104;
        s = st >> 2; t = st & 3; W = W1; K = 256;
    }
    float v[8];
#pragma unroll
    for (int j = 0; j < 8; ++j) {
        const int k = 32 * s + 8 * g + j;
        v[j] = (k < K) ? W[k * E_ + 16 * t + r] : 0.f;
    }
    uint4 u;
    u.x = pk2(v[0], v[1]); u.y = pk2(v[2], v[3]);
    u.z = pk2(v[4], v[5]); u.w = pk2(v[6], v[7]);
    frags[gid] = u;
}

// ---------------- Encoder: emb = x @ W + bias via MFMA ----------------
__global__ __launch_bounds__(256, 2) void enc_kernel(
    const float* __restrict__ traj, const uint4* __restrict__ frags,
    const float* __restrict__ bf_, const float* __restrict__ bu_,
    float* __restrict__ emb) {
    const int tid = threadIdx.x;
    const int lane = tid & 63;
    const int r = lane & 15, g = lane >> 4;
    const int mt = blockIdx.x * 4 + (tid >> 6);   // 0..1023
    const int b = mt >> 4;
    const int a0 = (mt & 15) * 16;
    const int role = (a0 >= NF_) ? 1 : 0;
    const uint4* __restrict__ wfr = frags + role * 52 * 64;

    float4 xa[ENC_KSTEPS], xb[ENC_KSTEPS];
#pragma unroll
    for (int s = 0; s < ENC_KSTEPS; ++s) {
        if (s < 12 || g < 2) {   // traj l-index = 4s+g must be < 50
            const float* p = traj + (((size_t)b * L_ + 4 * s + g) * A_ + a0 + r) * F_;
            xa[s] = *(const float4*)p;
            xb[s] = *(const float4*)(p + 4);
        } else {
            xa[s] = float4{0.f, 0.f, 0.f, 0.f};
            xb[s] = float4{0.f, 0.f, 0.f, 0.f};
        }
    }

    f32x4 acc[4];
#pragma unroll
    for (int t = 0; t < 4; ++t) acc[t] = (f32x4){0.f, 0.f, 0.f, 0.f};

#pragma unroll
    for (int s = 0; s < ENC_KSTEPS; ++s) {
        BF a;
        a.u[0] = pk2(xa[s].x, xa[s].y); a.u[1] = pk2(xa[s].z, xa[s].w);
        a.u[2] = pk2(xb[s].x, xb[s].y); a.u[3] = pk2(xb[s].z, xb[s].w);
#pragma unroll
        for (int t = 0; t < 4; ++t) {
            BF w; *(uint4*)w.u = wfr[(s * 4 + t) * 64 + lane];
            acc[t] = __builtin_amdgcn_mfma_f32_16x16x32_bf16(a.v, w.v, acc[t], 0, 0, 0);
        }
    }

    const float* __restrict__ bias = role ? bu_ : bf_;
    float bv[4];
#pragma unroll
    for (int t = 0; t < 4; ++t) bv[t] = bias[16 * t + r];
#pragma unroll
    for (int t = 0; t < 4; ++t)
#pragma unroll
        for (int reg = 0; reg < 4; ++reg) {
            const int row = a0 + 4 * g + reg;                  // agent within batch
            emb[((size_t)b * A_ + row) * E_ + 16 * t + r] = acc[t][reg] + bv[t];
        }
}

// ---------------- Classifier: rel(256) @ W1 -> relu -> @W2 ----------------
#define CLS_BLOCKS 4096
__global__ __launch_bounds__(256, 2) void cls_kernel(
    const float* __restrict__ emb, const int* __restrict__ pairs,
    const uint4* __restrict__ frags, const float* __restrict__ b1,
    const float* __restrict__ W2, const float* __restrict__ b2,
    float* __restrict__ out) {
    const int tid = threadIdx.x;
    const int lane = tid & 63;
    const int r = lane & 15;
    const int g = lane >> 4;

    __shared__ uint4 wlds[2048];          // W1 frag (s*4+t)*64+lane
#pragma unroll
    for (int it = 0; it < 8; ++it)
        wlds[tid + it * 256] = frags[W1_FRAG_OFF + tid + it * 256];
    __syncthreads();

    float b1v[4], w2v[4];
#pragma unroll
    for (int t = 0; t < 4; ++t) { b1v[t] = b1[16 * t + r]; w2v[t] = W2[16 * t + r]; }
    const float bias2 = b2[0];

    // one 16-pair tile per wave
    const int tile = blockIdx.x * 4 + (tid >> 6);  // 0..16383
    const int m0 = tile * 16;
    const int b = m0 >> 12;
    const int p = (m0 & (P_ - 1)) + r;
    const int2 pr = ((const int2*)pairs)[(size_t)b * P_ + p];
    const float* ef = emb + ((size_t)b * A_ + pr.x) * E_ + 8 * g;
    const float* eu = emb + ((size_t)b * A_ + pr.y) * E_ + 8 * g;

    const float4 f0a = *(const float4*)(ef);
    const float4 f0b = *(const float4*)(ef + 4);
    const float4 f1a = *(const float4*)(ef + 32);
    const float4 f1b = *(const float4*)(ef + 36);
    const float4 u0a = *(const float4*)(eu);
    const float4 u0b = *(const float4*)(eu + 4);
    const float4 u1a = *(const float4*)(eu + 32);
    const float4 u1b = *(const float4*)(eu + 36);

    auto pack = [](float4 x, float4 y) {
        BF o;
        o.u[0] = pk2(x.x, x.y); o.u[1] = pk2(x.z, x.w);
        o.u[2] = pk2(y.x, y.y); o.u[3] = pk2(y.z, y.w);
        return o;
    };
    auto adiff = [](float4 a, float4 b) {
        float4 o; o.x = fabsf(a.x - b.x); o.y = fabsf(a.y - b.y);
        o.z = fabsf(a.z - b.z); o.w = fabsf(a.w - b.w); return o;
    };
    auto mul4 = [](float4 a, float4 b) {
        float4 o; o.x = a.x * b.x; o.y = a.y * b.y;
        o.z = a.z * b.z; o.w = a.w * b.w; return o;
    };
    BF aF[8];
    aF[0] = pack(f0a, f0b);
    aF[1] = pack(f1a, f1b);
    aF[2] = pack(u0a, u0b);
    aF[3] = pack(u1a, u1b);
    aF[4] = pack(adiff(f0a, u0a), adiff(f0b, u0b));
    aF[5] = pack(adiff(f1a, u1a), adiff(f1b, u1b));
    aF[6] = pack(mul4(f0a, u0a), mul4(f0b, u0b));
    aF[7] = pack(mul4(f1a, u1a), mul4(f1b, u1b));

    f32x4 acc[4];
#pragma unroll
    for (int t = 0; t < 4; ++t) acc[t] = (f32x4){0.f, 0.f, 0.f, 0.f};
#pragma unroll
    for (int s = 0; s < 8; ++s) {
#pragma unroll
        for (int t = 0; t < 4; ++t) {
            BF bw; *(uint4*)bw.u = wlds[(s * 4 + t) * 64 + lane];
            acc[t] = __builtin_amdgcn_mfma_f32_16x16x32_bf16(aF[s].v, bw.v, acc[t], 0, 0, 0);
        }
    }

    float s0 = 0.f, s1 = 0.f, s2 = 0.f, s3 = 0.f;
#pragma unroll
    for (int t = 0; t < 4; ++t) {
        float h;
        h = acc[t][0] + b1v[t]; h = h > 0.f ? h : 0.f; s0 += h * w2v[t];
        h = acc[t][1] + b1v[t]; h = h > 0.f ? h : 0.f; s1 += h * w2v[t];
        h = acc[t][2] + b1v[t]; h = h > 0.f ? h : 0.f; s2 += h * w2v[t];
        h = acc[t][3] + b1v[t]; h = h > 0.f ? h : 0.f; s3 += h * w2v[t];
    }
#pragma unroll
    for (int m = 1; m < 16; m <<= 1) {
        s0 += __shfl_xor(s0, m);
        s1 += __shfl_xor(s1, m);
        s2 += __shfl_xor(s2, m);
        s3 += __shfl_xor(s3, m);
    }
    if (r < 4) {
        const float v = (r == 0) ? s0 : (r == 1) ? s1 : (r == 2) ? s2 : s3;
        out[m0 + 4 * g + r] = v + bias2;
    }
}

extern "C" void kernel_launch(void* const* d_in, const int* in_sizes, int n_in,
                              void* d_out, int out_size, void* d_ws, size_t ws_size,
                              hipStream_t stream) {
    const float* traj = (const float*)d_in[0];
    // d_in[1] = roles (unused; fixed by construction)
    const int*   pairs = (const int*)d_in[2];
    const float* Wf = (const float*)d_in[3];
    const float* bf = (const float*)d_in[4];
    const float* Wu = (const float*)d_in[5];
    const float* bu = (const float*)d_in[6];
    const float* W1 = (const float*)d_in[7];
    const float* b1 = (const float*)d_in[8];
    const float* W2 = (const float*)d_in[9];
    const float* b2 = (const float*)d_in[10];
    float* out = (float*)d_out;
    uint4* frags = (uint4*)d_ws;
    float* emb = (float*)d_ws + EMB_OFF;

    wprep_kernel<<<dim3((FRAG_TOTAL * 64 + 255) / 256), dim3(256), 0, stream>>>(Wf, Wu, W1, frags);
    // PROBE: enc and cls are idempotent; 3x each. dur delta vs single-launch
    // baseline (126.9us) = 2*(enc+cls).
    enc_kernel<<<dim3(256), dim3(256), 0, stream>>>(traj, frags, bf, bu, emb);
    cls_kernel<<<dim3(CLS_BLOCKS), dim3(256), 0, stream>>>(emb, pairs, frags, b1, W2, b2, out);
    enc_kernel<<<dim3(256), dim3(256), 0, stream>>>(traj, frags, bf, bu, emb);
    cls_kernel<<<dim3(CLS_BLOCKS), dim3(256), 0, stream>>>(emb, pairs, frags, b1, W2, b2, out);
    enc_kernel<<<dim3(256), dim3(256), 0, stream>>>(traj, frags, bf, bu, emb);
    cls_kernel<<<dim3(CLS_BLOCKS), dim3(256), 0, stream>>>(emb, pairs, frags, b1, W2, b2, out);
}

// Round 18
// 123.239 us; speedup vs baseline: 1.6642x; 1.6642x over previous
//
#include <hip/hip_runtime.h>
#include <hip/hip_bf16.h>

#define B_  64
#define L_  50
#define A_  256
#define F_  8
#define E_  64
#define P_  4096
#define NF_ 128
#define NEMB (B_ * A_ * E_)   // 1,048,576 floats = 4 MB

typedef __attribute__((ext_vector_type(8))) short bhalf8;
typedef __attribute__((ext_vector_type(4))) float f32x4;

union BF { bhalf8 v; unsigned u[4]; short s[8]; };

static __device__ __forceinline__ unsigned pk2(float lo, float hi) {
    __hip_bfloat162 h = __float22bfloat162_rn(float2{lo, hi});  // RNE, lo in low 16
    union { __hip_bfloat162 h; unsigned u; } c; c.h = h;
    return c.u;
}

// Fragment convention (verified passing rounds 4/5/7/15/17, absmax <= 0.0176):
//   A-frag (lane l): row=l&15,  k=32s+8*(l>>4)+j (j=0..7)
//   B-frag (lane l): col=l&15,  same k
//   C/D   (lane l): col=l&15,  row=4*(l>>4)+reg
//
// Round-18 structure (probe r17: enc+cls = 39us, fixed floor = 88us):
//   enc split-K: wave = (m-tile, K-half). K-half h covers l in [25h, 25h+25)
//     -> k_local = 32s+8g+j (7 ksteps, guard 4s+g<25), global k = 200h+k_local.
//     2048 waves (2x TLP), writes fp32 part[2][B][A][E].
//   red: emb = part0 + part1 + bias (12 MB traffic).
//   cls: TPW=4 @1024 blocks -> W1 LDS staging traffic /4.
//
// ws layout (floats): frags 144*64 uint4 = 147,456 B at 0; part[2] at 65536
// (2 x 1M floats); emb at 65536 + 2*NEMB.
//   fid = role*56 + half*28 + s*4 + t   (role<2, half<2, s<7, t<4)  -> 0..111
//   fid 112..143: cls W1 frags (s<8, t<4), K=256

#define ENC_KSTEPS 7
#define FRAG_TOTAL 144
#define W1_FRAG_OFF (112 * 64)
#define PART_OFF 65536

// ---------------- wprep: pack Wf/Wu/W1 into bf16 MFMA B-fragments ----------
__global__ __launch_bounds__(256) void wprep_kernel(
    const float* __restrict__ Wf, const float* __restrict__ Wu,
    const float* __restrict__ W1, uint4* __restrict__ frags) {
    const int gid = blockIdx.x * 256 + threadIdx.x;
    if (gid >= FRAG_TOTAL * 64) return;
    const int fid = gid >> 6, lane = gid & 63;
    const int r = lane & 15, g = lane >> 4;
    float v[8];
    if (fid < 112) {
        const int role = fid / 56;
        const int rem = fid % 56;
        const int half = rem / 28;
        const int s = (rem % 28) >> 2, t = rem & 3;
        const float* W = role ? Wu : Wf;
#pragma unroll
        for (int j = 0; j < 8; ++j) {
            const int kl = 32 * s + 8 * g + j;            // k within half, <224
            v[j] = (kl < 200) ? W[(200 * half + kl) * E_ + 16 * t + r] : 0.f;
        }
    } else {
        const int st = fid - 112;
        const int s = st >> 2, t = st & 3;
#pragma unroll
        for (int j = 0; j < 8; ++j) {
            const int k = 32 * s + 8 * g + j;             // < 256 always
            v[j] = W1[k * E_ + 16 * t + r];
        }
    }
    uint4 u;
    u.x = pk2(v[0], v[1]); u.y = pk2(v[2], v[3]);
    u.z = pk2(v[4], v[5]); u.w = pk2(v[6], v[7]);
    frags[gid] = u;
}

// ---------------- Encoder (split-K): part[half] = x[:, 200h:200h+200] @ W ---
// 512 blocks x 4 waves = 2048 waves; wave = (m-tile mt, half).
__global__ __launch_bounds__(256, 2) void enc_kernel(
    const float* __restrict__ traj, const uint4* __restrict__ frags,
    float* __restrict__ part) {
    const int tid = threadIdx.x;
    const int lane = tid & 63;
    const int r = lane & 15, g = lane >> 4;
    const int wid = blockIdx.x * 4 + (tid >> 6);  // 0..2047
    const int mt = wid >> 1;                      // 0..1023
    const int half = wid & 1;
    const int b = mt >> 4;
    const int a0 = (mt & 15) * 16;
    const int role = (a0 >= NF_) ? 1 : 0;
    const uint4* __restrict__ wfr = frags + (role * 56 + half * 28) * 64;

    float4 xa[ENC_KSTEPS], xb[ENC_KSTEPS];
#pragma unroll
    for (int s = 0; s < ENC_KSTEPS; ++s) {
        if (4 * s + g < 25) {                     // l_local = 4s+g must be < 25
            const int l = 25 * half + 4 * s + g;
            const float* p = traj + (((size_t)b * L_ + l) * A_ + a0 + r) * F_;
            xa[s] = *(const float4*)p;
            xb[s] = *(const float4*)(p + 4);
        } else {
            xa[s] = float4{0.f, 0.f, 0.f, 0.f};
            xb[s] = float4{0.f, 0.f, 0.f, 0.f};
        }
    }

    f32x4 acc[4];
#pragma unroll
    for (int t = 0; t < 4; ++t) acc[t] = (f32x4){0.f, 0.f, 0.f, 0.f};

#pragma unroll
    for (int s = 0; s < ENC_KSTEPS; ++s) {
        BF a;
        a.u[0] = pk2(xa[s].x, xa[s].y); a.u[1] = pk2(xa[s].z, xa[s].w);
        a.u[2] = pk2(xb[s].x, xb[s].y); a.u[3] = pk2(xb[s].z, xb[s].w);
#pragma unroll
        for (int t = 0; t < 4; ++t) {
            BF w; *(uint4*)w.u = wfr[(s * 4 + t) * 64 + lane];
            acc[t] = __builtin_amdgcn_mfma_f32_16x16x32_bf16(a.v, w.v, acc[t], 0, 0, 0);
        }
    }

#pragma unroll
    for (int t = 0; t < 4; ++t)
#pragma unroll
        for (int reg = 0; reg < 4; ++reg) {
            const int row = a0 + 4 * g + reg;
            part[(size_t)half * NEMB + ((size_t)b * A_ + row) * E_ + 16 * t + r] = acc[t][reg];
        }
}

// ---------------- Reduce: emb = part0 + part1 + bias ----------------
__global__ __launch_bounds__(256) void red_kernel(
    const float* __restrict__ part, const float* __restrict__ bf_,
    const float* __restrict__ bu_, float* __restrict__ emb) {
    const int idx = (blockIdx.x * 256 + threadIdx.x) * 4;   // 1024 blocks
    const float4 p0 = *(const float4*)(part + idx);
    const float4 p1 = *(const float4*)(part + NEMB + idx);
    const int a = (idx >> 6) & (A_ - 1);
    const float* bias = (a < NF_) ? bf_ : bu_;
    const float4 bv = *(const float4*)(bias + (idx & 63));
    float4 o;
    o.x = p0.x + p1.x + bv.x; o.y = p0.y + p1.y + bv.y;
    o.z = p0.z + p1.z + bv.z; o.w = p0.w + p1.w + bv.w;
    *(float4*)(emb + idx) = o;
}

// ---------------- Classifier: rel(256) @ W1 -> relu -> @W2 ----------------
#define CLS_BLOCKS 1024
#define TPW 4
__global__ __launch_bounds__(256, 2) void cls_kernel(
    const float* __restrict__ emb, const int* __restrict__ pairs,
    const uint4* __restrict__ frags, const float* __restrict__ b1,
    const float* __restrict__ W2, const float* __restrict__ b2,
    float* __restrict__ out) {
    const int tid = threadIdx.x;
    const int lane = tid & 63;
    const int r = lane & 15;
    const int g = lane >> 4;

    __shared__ uint4 wlds[2048];          // W1 frag (s*4+t)*64+lane
#pragma unroll
    for (int it = 0; it < 8; ++it)
        wlds[tid + it * 256] = frags[W1_FRAG_OFF + tid + it * 256];
    __syncthreads();

    float b1v[4], w2v[4];
#pragma unroll
    for (int t = 0; t < 4; ++t) { b1v[t] = b1[16 * t + r]; w2v[t] = W2[16 * t + r]; }
    const float bias2 = b2[0];
    const int wid = blockIdx.x * 4 + (tid >> 6);   // 0..4095

    for (int ti = 0; ti < TPW; ++ti) {
        const int tile = wid * TPW + ti;           // 16384 tiles
        const int m0 = tile * 16;
        const int b = m0 >> 12;
        const int p = (m0 & (P_ - 1)) + r;
        const int2 pr = ((const int2*)pairs)[(size_t)b * P_ + p];
        const float* ef = emb + ((size_t)b * A_ + pr.x) * E_ + 8 * g;
        const float* eu = emb + ((size_t)b * A_ + pr.y) * E_ + 8 * g;

        const float4 f0a = *(const float4*)(ef);
        const float4 f0b = *(const float4*)(ef + 4);
        const float4 f1a = *(const float4*)(ef + 32);
        const float4 f1b = *(const float4*)(ef + 36);
        const float4 u0a = *(const float4*)(eu);
        const float4 u0b = *(const float4*)(eu + 4);
        const float4 u1a = *(const float4*)(eu + 32);
        const float4 u1b = *(const float4*)(eu + 36);

        auto pack = [](float4 x, float4 y) {
            BF o;
            o.u[0] = pk2(x.x, x.y); o.u[1] = pk2(x.z, x.w);
            o.u[2] = pk2(y.x, y.y); o.u[3] = pk2(y.z, y.w);
            return o;
        };
        auto adiff = [](float4 a, float4 b) {
            float4 o; o.x = fabsf(a.x - b.x); o.y = fabsf(a.y - b.y);
            o.z = fabsf(a.z - b.z); o.w = fabsf(a.w - b.w); return o;
        };
        auto mul4 = [](float4 a, float4 b) {
            float4 o; o.x = a.x * b.x; o.y = a.y * b.y;
            o.z = a.z * b.z; o.w = a.w * b.w; return o;
        };
        BF aF[8];
        aF[0] = pack(f0a, f0b);
        aF[1] = pack(f1a, f1b);
        aF[2] = pack(u0a, u0b);
        aF[3] = pack(u1a, u1b);
        aF[4] = pack(adiff(f0a, u0a), adiff(f0b, u0b));
        aF[5] = pack(adiff(f1a, u1a), adiff(f1b, u1b));
        aF[6] = pack(mul4(f0a, u0a), mul4(f0b, u0b));
        aF[7] = pack(mul4(f1a, u1a), mul4(f1b, u1b));

        f32x4 acc[4];
#pragma unroll
        for (int t = 0; t < 4; ++t) acc[t] = (f32x4){0.f, 0.f, 0.f, 0.f};
#pragma unroll
        for (int s = 0; s < 8; ++s) {
#pragma unroll
            for (int t = 0; t < 4; ++t) {
                BF bw; *(uint4*)bw.u = wlds[(s * 4 + t) * 64 + lane];
                acc[t] = __builtin_amdgcn_mfma_f32_16x16x32_bf16(aF[s].v, bw.v, acc[t], 0, 0, 0);
            }
        }

        float s0 = 0.f, s1 = 0.f, s2 = 0.f, s3 = 0.f;
#pragma unroll
        for (int t = 0; t < 4; ++t) {
            float h;
            h = acc[t][0] + b1v[t]; h = h > 0.f ? h : 0.f; s0 += h * w2v[t];
            h = acc[t][1] + b1v[t]; h = h > 0.f ? h : 0.f; s1 += h * w2v[t];
            h = acc[t][2] + b1v[t]; h = h > 0.f ? h : 0.f; s2 += h * w2v[t];
            h = acc[t][3] + b1v[t]; h = h > 0.f ? h : 0.f; s3 += h * w2v[t];
        }
#pragma unroll
        for (int m = 1; m < 16; m <<= 1) {
            s0 += __shfl_xor(s0, m);
            s1 += __shfl_xor(s1, m);
            s2 += __shfl_xor(s2, m);
            s3 += __shfl_xor(s3, m);
        }
        if (r < 4) {
            const float v = (r == 0) ? s0 : (r == 1) ? s1 : (r == 2) ? s2 : s3;
            out[m0 + 4 * g + r] = v + bias2;
        }
    }
}

extern "C" void kernel_launch(void* const* d_in, const int* in_sizes, int n_in,
                              void* d_out, int out_size, void* d_ws, size_t ws_size,
                              hipStream_t stream) {
    const float* traj = (const float*)d_in[0];
    // d_in[1] = roles (unused; fixed by construction)
    const int*   pairs = (const int*)d_in[2];
    const float* Wf = (const float*)d_in[3];
    const float* bf = (const float*)d_in[4];
    const float* Wu = (const float*)d_in[5];
    const float* bu = (const float*)d_in[6];
    const float* W1 = (const float*)d_in[7];
    const float* b1 = (const float*)d_in[8];
    const float* W2 = (const float*)d_in[9];
    const float* b2 = (const float*)d_in[10];
    float* out = (float*)d_out;
    uint4* frags = (uint4*)d_ws;
    float* part = (float*)d_ws + PART_OFF;         // 2 x 4 MB
    float* emb  = (float*)d_ws + PART_OFF + 2 * NEMB;

    wprep_kernel<<<dim3((FRAG_TOTAL * 64 + 255) / 256), dim3(256), 0, stream>>>(Wf, Wu, W1, frags);
    enc_kernel<<<dim3(512), dim3(256), 0, stream>>>(traj, frags, part);
    red_kernel<<<dim3(1024), dim3(256), 0, stream>>>(part, bf, bu, emb);
    cls_kernel<<<dim3(CLS_BLOCKS), dim3(256), 0, stream>>>(emb, pairs, frags, b1, W2, b2, out);
}